// Round 11
// baseline (567.468 us; speedup 1.0000x reference)
//
#include <hip/hip_runtime.h>

// LAM module: out = gamma * (softmax(rowmax(E)-E) @ q) + x,  E = cosine-sim(q,q)
// B=2, N=32, D = 64*128*128 = 1,048,576, all fp32.
//
//  k_zero : zero 8 partial-Gram slots in ws
//  k_gram : G[b] = q q^T via bf16 MFMA, LDS-staged, T14 prefetch pipeline
//  k_attn : tiny 32x32 softmax; M = gamma*attention + I  (folds residual)
//  k_apply: out = M @ q, m-group pipelined loads, nontemporal stores

#define NROW 32
static const size_t D_FULL = 1048576ull;   // 64*128*128
#define EPSN 1e-12f

typedef __attribute__((ext_vector_type(8)))  __bf16 bf16x8;
typedef __attribute__((ext_vector_type(4)))  __bf16 bf16x4;
typedef __attribute__((ext_vector_type(16))) float  f32x16;
typedef __attribute__((ext_vector_type(4)))  float  f32x4;

// ---------------------------------------------------------------- k_zero ----
__global__ __launch_bounds__(256) void k_zero(float* g) {
    int i = blockIdx.x * 256 + threadIdx.x;
    ((float4*)g)[i] = make_float4(0.f, 0.f, 0.f, 0.f);
}

// ---------------------------------------------------------------- k_gram ----
// grid = 1024 blocks (512/batch), block = 256 (4 waves), 4 blocks/CU.
// Block owns 32 rows x 2048 cols as 4 subtiles of 512 cols, SW-pipelined:
//   regs hold subtile s; per iter: convert+LDS-write s, barrier,
//   ISSUE loads for s+1 (in flight during compute), then MFMA on s.
// LDS row stride 520 bf16 (65*16 B): rows 16B-aligned, odd multiplier
// rotates row-starts across the 8 quad-banks -> conflict-free b128 reads.
#define GSTRIDE 520
__global__ __launch_bounds__(256, 4) void k_gram(const float* __restrict__ x,
                                                 float* __restrict__ gpart) {
    __shared__ __align__(16) unsigned char smem[NROW * GSTRIDE * 2]; // 33280 B
    __bf16* tile = (__bf16*)smem;
    float (*red)[1024] = (float (*)[1024])smem;   // overlay, used after k-loop

    const int tid  = threadIdx.x;
    const int w    = tid >> 6;
    const int lane = tid & 63;
    const int b    = (int)(blockIdx.x >> 9);              // 0..1
    const size_t dblk = ((size_t)(blockIdx.x & 511)) * 2048;
    const int row  = lane & 31;
    const int kg   = lane >> 5;

    const float* xb = x + (size_t)b * NROW * D_FULL + dblk;
    const int srow0 = tid >> 7;        // 0/1: row parity this thread stages
    const int sc4   = tid & 127;       // float4 col within 512-col subtile

    f32x16 acc = (f32x16)(0.0f);
    float4 vreg[16];

    // prologue: load subtile 0 into regs
    #pragma unroll
    for (int sw = 0; sw < 16; ++sw) {
        int r = sw * 2 + srow0;
        vreg[sw] = *(const float4*)(xb + (size_t)r * D_FULL + sc4 * 4);
    }

    for (int s = 0; s < 4; ++s) {
        __syncthreads();                  // prev subtile's ds_reads complete
        #pragma unroll
        for (int sw = 0; sw < 16; ++sw) { // convert + stage current subtile
            int r = sw * 2 + srow0;
            float4 v = vreg[sw];
            bf16x4 h;
            h[0] = (__bf16)v.x; h[1] = (__bf16)v.y;
            h[2] = (__bf16)v.z; h[3] = (__bf16)v.w;
            *(bf16x4*)&tile[r * GSTRIDE + sc4 * 4] = h;
        }
        __syncthreads();
        if (s < 3) {                      // issue next subtile's loads NOW;
            const float* src = xb + (s + 1) * 512;   // in flight during MFMA
            #pragma unroll
            for (int sw = 0; sw < 16; ++sw) {
                int r = sw * 2 + srow0;
                vreg[sw] = *(const float4*)(src + (size_t)r * D_FULL + sc4 * 4);
            }
        }
        #pragma unroll
        for (int kk = 0; kk < 8; ++kk) {
            int kstep = w * 8 + kk;
            bf16x8 f = *(const bf16x8*)&tile[row * GSTRIDE + kstep * 16 + kg * 8];
            acc = __builtin_amdgcn_mfma_f32_32x32x16_bf16(f, f, acc, 0, 0, 0);
        }
    }
    __syncthreads();   // all tile reads done before red overlays the tile

    // C/D layout (verified m74/m101): col = lane&31, row = (r&3)+8*(r>>2)+4*(lane>>5)
    const int col  = lane & 31;
    const int rsel = lane >> 5;
    #pragma unroll
    for (int r = 0; r < 16; ++r) {
        int rw = (r & 3) + 8 * (r >> 2) + 4 * rsel;
        red[w][rw * 32 + col] = acc[r];
    }
    __syncthreads();

    float* dst = gpart + (size_t)(blockIdx.x & 7) * 2048 + (size_t)b * 1024;
    for (int e = tid; e < 1024; e += 256) {
        float sum = red[0][e] + red[1][e] + red[2][e] + red[3][e];
        atomicAdd(&dst[e], sum);
    }
}

// ---------------------------------------------------------------- k_attn ----
__global__ __launch_bounds__(1024) void k_attn(const float* __restrict__ gpart,
                                               const float* __restrict__ gamma_p,
                                               float* __restrict__ M) {
    const int b   = blockIdx.x;
    const int tid = threadIdx.x;
    const int n   = tid >> 5;
    const int m   = tid & 31;

    float g = 0.f;
    #pragma unroll
    for (int s = 0; s < 8; ++s) g += gpart[(size_t)s * 2048 + (size_t)b * 1024 + tid];

    __shared__ float nrm[32];
    if (n == m) nrm[n] = fmaxf(sqrtf(g), EPSN);
    __syncthreads();

    float e = g / (nrm[n] * nrm[m]);

    float rmin = e;
    #pragma unroll
    for (int off = 16; off > 0; off >>= 1) rmin = fminf(rmin, __shfl_xor(rmin, off, 32));
    // softmax(rowmax - e) == exp(rmin - e) / sum(exp(rmin - e))
    float pv  = expf(rmin - e);
    float sum = pv;
    #pragma unroll
    for (int off = 16; off > 0; off >>= 1) sum += __shfl_xor(sum, off, 32);
    float a = pv / sum;

    M[(size_t)b * 1024 + tid] = gamma_p[0] * a + (n == m ? 1.f : 0.f);
}

// --------------------------------------------------------------- k_apply ----
// out = M @ q.  grid = 2048 blocks (1024/batch), block = 256.
// m-group pipeline: accumulate o[32] over 4 groups of 8 rows; while group g
// is consumed by FMAs, group g+1's 8 loads are in flight (ping-pong qa/qb).
// Smooth memory demand (no load-drain-compute convoy). Nontemporal stores:
// out is never re-read; keeps x resident in L3 for the read stream.
__device__ __forceinline__ void fma4(float4& o, float c, const float4& a) {
    o.x += c * a.x; o.y += c * a.y; o.z += c * a.z; o.w += c * a.w;
}

#define ACC8(Q, MB)                                               \
    _Pragma("unroll")                                             \
    for (int n = 0; n < 32; ++n) {                                \
        const float4 c0 = *(const float4*)&Ml[n * 32 + (MB)];     \
        const float4 c1 = *(const float4*)&Ml[n * 32 + (MB) + 4]; \
        fma4(o[n], c0.x, Q[0]); fma4(o[n], c0.y, Q[1]);           \
        fma4(o[n], c0.z, Q[2]); fma4(o[n], c0.w, Q[3]);           \
        fma4(o[n], c1.x, Q[4]); fma4(o[n], c1.y, Q[5]);           \
        fma4(o[n], c1.z, Q[6]); fma4(o[n], c1.w, Q[7]);           \
    }

__global__ __launch_bounds__(256, 2) void k_apply(const float* __restrict__ x,
                                                  const float* __restrict__ M,
                                                  float* __restrict__ out) {
    __shared__ __align__(16) float Ml[1024];
    const int tid = threadIdx.x;
    const int b   = blockIdx.x >> 10;
    const float* Mb = M + (size_t)b * 1024;
    #pragma unroll
    for (int i = 0; i < 4; ++i) Ml[tid + i * 256] = Mb[tid + i * 256];
    __syncthreads();

    const size_t d4  = ((size_t)(blockIdx.x & 1023)) * 256 + tid;
    const size_t rs4 = D_FULL / 4;
    const float4* xb = (const float4*)(x) + (size_t)b * NROW * rs4;
    f32x4*        ob = (f32x4*)(out)      + (size_t)b * NROW * rs4;

    float4 o[32];
    #pragma unroll
    for (int n = 0; n < 32; ++n) o[n] = make_float4(0.f, 0.f, 0.f, 0.f);

    float4 qa[8], qb[8];
    #pragma unroll
    for (int m = 0; m < 8; ++m) qa[m] = xb[(size_t)m * rs4 + d4];        // g0
    #pragma unroll
    for (int m = 0; m < 8; ++m) qb[m] = xb[(size_t)(8 + m) * rs4 + d4];  // g1
    ACC8(qa, 0)                                                          // use g0
    #pragma unroll
    for (int m = 0; m < 8; ++m) qa[m] = xb[(size_t)(16 + m) * rs4 + d4]; // g2
    ACC8(qb, 8)                                                          // use g1
    #pragma unroll
    for (int m = 0; m < 8; ++m) qb[m] = xb[(size_t)(24 + m) * rs4 + d4]; // g3
    ACC8(qa, 16)                                                         // use g2
    ACC8(qb, 24)                                                         // use g3

    #pragma unroll
    for (int n = 0; n < 32; ++n) {
        f32x4 ov; ov[0] = o[n].x; ov[1] = o[n].y; ov[2] = o[n].z; ov[3] = o[n].w;
        __builtin_nontemporal_store(ov, &ob[(size_t)n * rs4 + d4]);
    }
}

// ------------------------------------------------------------------ entry ---
extern "C" void kernel_launch(void* const* d_in, const int* in_sizes, int n_in,
                              void* d_out, int out_size, void* d_ws, size_t ws_size,
                              hipStream_t stream) {
    const float* x     = (const float*)d_in[0];
    const float* gamma = (const float*)d_in[1];
    float*       out   = (float*)d_out;
    float*       ws    = (float*)d_ws;

    float* gpart = ws;            // 8 slots * 2 batches * 1024 = 16384 floats
    float* Mws   = ws + 16384;    // 2 * 1024 floats

    k_zero <<<16,   256,  0, stream>>>(gpart);
    k_gram <<<1024, 256,  0, stream>>>(x, gpart);
    k_attn <<<2,    1024, 0, stream>>>(gpart, gamma, Mws);
    k_apply<<<2048, 256,  0, stream>>>(x, Mws, out);
}